// Round 15
// baseline (843.720 us; speedup 1.0000x reference)
//
#include <hip/hip_runtime.h>

#define IN_F 128
#define HRH 4            // src-hist node-ranges (LDS 50KB)
#define HCS 32           // src-hist edge chunks
#define HIST_RS 12544    // >= ceil(nN/HRH)
#define RSH 6            // dst range shift: range = 64 nodes
#define RANGE 64
#define NC 256           // edge chunks for coarse count / place
#define NRP 1024         // padded range count (scan width)
#define LROWF 132        // LDS fp32 row stride (132 = 4 mod 32 banks: MFMA A-reads hit min conflicts)

typedef __attribute__((ext_vector_type(8))) short bf16x8;
typedef __attribute__((ext_vector_type(4))) float f32x4;

static __device__ __forceinline__ unsigned short f2bf(float x) {
    unsigned u = __float_as_uint(x);
    return (unsigned short)((u + 0x7FFFu + ((u >> 16) & 1u)) >> 16);
}
#define RFL(x) __builtin_amdgcn_readfirstlane(x)

// ---- K1: per-node src histogram (privatized) + coarse dst-range counts ----
__global__ __launch_bounds__(256) void k_hist(const int* __restrict__ src,
                                              const int* __restrict__ dst,
                                              int* __restrict__ srcpart,
                                              int* __restrict__ ctab,
                                              int nN, int nE, int NR) {
    __shared__ int hh[HIST_RS];
    const int bid = blockIdx.x;
    if (bid < HRH * HCS) {
        const int r = bid / HCS, c = bid % HCS;
        const int rs = (nN + HRH - 1) / HRH;
        const int rbeg = r * rs;
        const int rsize = min(rs, nN - rbeg);
        if (rsize <= 0) return;
        for (int i = threadIdx.x; i < rsize; i += 256) hh[i] = 0;
        __syncthreads();
        const int chunk = (nE + HCS - 1) / HCS;
        const int ebeg = c * chunk, eend = min(ebeg + chunk, nE);
        for (int i = ebeg + threadIdx.x * 4; i < eend; i += 1024) {
            if (i + 3 < eend) {
                const int4 k4 = *reinterpret_cast<const int4*>(src + i);
                int a;
                a = k4.x - rbeg; if ((unsigned)a < (unsigned)rsize) atomicAdd(&hh[a], 1);
                a = k4.y - rbeg; if ((unsigned)a < (unsigned)rsize) atomicAdd(&hh[a], 1);
                a = k4.z - rbeg; if ((unsigned)a < (unsigned)rsize) atomicAdd(&hh[a], 1);
                a = k4.w - rbeg; if ((unsigned)a < (unsigned)rsize) atomicAdd(&hh[a], 1);
            } else {
                for (int j = i; j < eend; ++j) {
                    int a = src[j] - rbeg;
                    if ((unsigned)a < (unsigned)rsize) atomicAdd(&hh[a], 1);
                }
            }
        }
        __syncthreads();
        int* pout = srcpart + (size_t)c * nN + rbeg;
        for (int i = threadIdx.x; i < rsize; i += 256) pout[i] = hh[i];
    } else {
        const int c = bid - HRH * HCS;
        for (int i = threadIdx.x; i < NR; i += 256) hh[i] = 0;
        __syncthreads();
        const int chunk = (nE + NC - 1) / NC;
        const int ebeg = c * chunk, eend = min(ebeg + chunk, nE);
        for (int i = ebeg + threadIdx.x; i < eend; i += 256)
            atomicAdd(&hh[dst[i] >> RSH], 1);
        __syncthreads();
        int* pout = ctab + (size_t)c * NR;
        for (int i = threadIdx.x; i < NR; i += 256) pout[i] = hh[i];
    }
}

// ---- K2: scale h (with inline src-degree) | ctab scan | wt convert ----
__global__ __launch_bounds__(256) void k_prep2(
    const float* __restrict__ feat, const int* __restrict__ srcpart,
    unsigned short* __restrict__ h, int* __restrict__ ctab,
    int* __restrict__ range_base, const float* __restrict__ W,
    unsigned short* __restrict__ wt, int nN, int nE, int NR, int SCB) {
    const int b = blockIdx.x;
    const int t = threadIdx.x;
    if (b < SCB) {
        // 8 nodes per block: recompute src-degree, scale 128 feats -> bf16
        __shared__ int ssum[256];
        __shared__ float sdinv[8];
        const int nb = b * 8;
        const int nl = t >> 5, c = t & 31;
        const int node = nb + nl;
        ssum[t] = (node < nN) ? srcpart[(size_t)c * nN + node] : 0;
        __syncthreads();
        if (t < 8) {
            int s = 0;
#pragma unroll
            for (int c2 = 0; c2 < 32; ++c2) s += ssum[t * 32 + c2];
            sdinv[t] = rsqrtf(fmaxf((float)s, 1.0f));
        }
        __syncthreads();
        const int node2 = nb + (t >> 5);
        if (node2 < nN) {
            const int j = (t * 4) & 127;
            const float s = sdinv[t >> 5];
            const float4 v = *reinterpret_cast<const float4*>(feat + (size_t)node2 * IN_F + j);
            ushort4 o;
            o.x = f2bf(v.x * s); o.y = f2bf(v.y * s);
            o.z = f2bf(v.z * s); o.w = f2bf(v.w * s);
            *reinterpret_cast<ushort4*>(h + (size_t)node2 * IN_F + j) = o;
        }
    } else if (b == SCB) {
        // within-range chunk prefixes + exclusive range bases
        __shared__ int rt[NRP];
        int own[NRP / 256];
#pragma unroll
        for (int k = 0; k < NRP / 256; ++k) {
            const int rr = t + k * 256;
            int run = 0;
            if (rr < NR) {
                for (int c = 0; c < NC; ++c) {
                    const size_t idx = (size_t)c * NR + rr;
                    const int v = ctab[idx];
                    ctab[idx] = run;
                    run += v;
                }
            }
            rt[rr] = run;
            own[k] = run;
        }
        __syncthreads();
        for (int d = 1; d < NRP; d <<= 1) {
            int tmp[NRP / 256];
#pragma unroll
            for (int k = 0; k < NRP / 256; ++k) {
                const int i = t + k * 256;
                tmp[k] = (i >= d) ? rt[i - d] : 0;
            }
            __syncthreads();
#pragma unroll
            for (int k = 0; k < NRP / 256; ++k) rt[t + k * 256] += tmp[k];
            __syncthreads();
        }
#pragma unroll
        for (int k = 0; k < NRP / 256; ++k) {
            const int rr = t + k * 256;
            if (rr < NR) {
                range_base[rr] = rt[rr] - own[k];
                if (rr == NR - 1) range_base[NR] = rt[rr];
            }
        }
    } else {
        const int tt = (b - SCB - 1) * 256 + t;
        if (tt < 128 * 128) {
            const int col = tt >> 7, k = tt & 127;
            wt[col * 128 + k] = f2bf(W[k * 128 + col]);
        }
    }
}

// ---- K3: place edges into coarse range bins as (src,dst) pairs ----
__global__ __launch_bounds__(256) void k_place(const int* __restrict__ src,
                                               const int* __restrict__ dst,
                                               const int* __restrict__ ctab,
                                               const int* __restrict__ range_base,
                                               uint2* __restrict__ pairs,
                                               int nE, int NR) {
    __shared__ int cur[NRP];
    const int c = blockIdx.x;
    for (int i = threadIdx.x; i < NR; i += 256)
        cur[i] = range_base[i] + ctab[(size_t)c * NR + i];
    __syncthreads();
    const int chunk = (nE + NC - 1) / NC;
    const int ebeg = c * chunk, eend = min(ebeg + chunk, nE);
    for (int i = ebeg + threadIdx.x; i < eend; i += 256) {
        const int s = src[i], d = dst[i];
        const int p = atomicAdd(&cur[d >> RSH], 1);
        pairs[p] = make_uint2((unsigned)s, (unsigned)d);
    }
}

// ---- K4: fused scatter(LDS fp32) + in-degree + GEMM + epilogue ----
// block = 64-node dst range; 4 waves split the range's edge list; 16 gathers
// in flight per wave (scalar pair path); ds_add_f32 accumulate; then 4x
// 16-row MFMA tiles (A from LDS fp32 -> bf16 cvt), dinv_in from LDS counts.
__global__ __launch_bounds__(256) void k_main(
    const unsigned short* __restrict__ h, const uint2* __restrict__ pairs,
    const int* __restrict__ range_base, const unsigned short* __restrict__ wt,
    const float* __restrict__ bias, float* __restrict__ out, int nN) {
    __shared__ float accL[RANGE * LROWF];
    __shared__ int cntL[RANGE];
    const int lane = threadIdx.x & 63;
    const int wave = threadIdx.x >> 6;
    const int r = blockIdx.x;
    const int rbeg = r * RANGE;

    for (int i = threadIdx.x; i < RANGE * LROWF; i += 256) accL[i] = 0.0f;
    if (threadIdx.x < RANGE) cntL[threadIdx.x] = 0;
    __syncthreads();

    const int off  = RFL(range_base[r]);
    const int cend = RFL(range_base[r + 1]);
    const int cnt  = cend - off;
    const int qb = off + (cnt * wave) / 4;
    const int qe = off + (cnt * (wave + 1)) / 4;
    const int lo2 = lane * 2;

    int i = qb;
    for (; i + 16 <= qe; i += 16) {
        uint2 P[16];
#pragma unroll
        for (int k = 0; k < 16; ++k) P[k] = pairs[RFL(i) + k];
        unsigned v[16];
#pragma unroll
        for (int k = 0; k < 16; ++k)
            v[k] = *reinterpret_cast<const unsigned*>(h + (size_t)RFL((int)P[k].x) * IN_F + lo2);
#pragma unroll
        for (int k = 0; k < 16; ++k) {
            const int dl = RFL((int)P[k].y) - rbeg;
            atomicAdd(&accL[dl * LROWF + lo2],     __uint_as_float(v[k] << 16));
            atomicAdd(&accL[dl * LROWF + lo2 + 1], __uint_as_float(v[k] & 0xFFFF0000u));
            if (lane == 0) atomicAdd(&cntL[dl], 1);
        }
    }
    for (; i < qe; ++i) {
        const uint2 P = pairs[RFL(i)];
        const unsigned vv = *reinterpret_cast<const unsigned*>(h + (size_t)RFL((int)P.x) * IN_F + lo2);
        const int dl = RFL((int)P.y) - rbeg;
        atomicAdd(&accL[dl * LROWF + lo2],     __uint_as_float(vv << 16));
        atomicAdd(&accL[dl * LROWF + lo2 + 1], __uint_as_float(vv & 0xFFFF0000u));
        if (lane == 0) atomicAdd(&cntL[dl], 1);
    }
    __syncthreads();

    // GEMM: wave w -> local rows [w*16, w*16+16)
    const int g = lane >> 4, cl = lane & 15;
    const int lr = wave * 16 + cl;
    bf16x8 a[4];
#pragma unroll
    for (int s = 0; s < 4; ++s) {
        const float* ap = accL + lr * LROWF + s * 32 + g * 8;
        const float4 u0 = *reinterpret_cast<const float4*>(ap);
        const float4 u1 = *reinterpret_cast<const float4*>(ap + 4);
        bf16x8 aa;
        aa[0] = (short)f2bf(u0.x); aa[1] = (short)f2bf(u0.y);
        aa[2] = (short)f2bf(u0.z); aa[3] = (short)f2bf(u0.w);
        aa[4] = (short)f2bf(u1.x); aa[5] = (short)f2bf(u1.y);
        aa[6] = (short)f2bf(u1.z); aa[7] = (short)f2bf(u1.w);
        a[s] = aa;
    }
    float di[4];
#pragma unroll
    for (int q = 0; q < 4; ++q)
        di[q] = rsqrtf(fmaxf((float)cntL[wave * 16 + g * 4 + q], 1.0f));

    f32x4 acc[8];
#pragma unroll
    for (int t2 = 0; t2 < 8; ++t2) acc[t2] = (f32x4){0.f, 0.f, 0.f, 0.f};
#pragma unroll
    for (int s = 0; s < 4; ++s) {
#pragma unroll
        for (int t2 = 0; t2 < 8; ++t2) {
            const int col = t2 * 16 + cl;
            const bf16x8 bb = *reinterpret_cast<const bf16x8*>(wt + (size_t)col * IN_F + s * 32 + g * 8);
            acc[t2] = __builtin_amdgcn_mfma_f32_16x16x32_bf16(a[s], bb, acc[t2], 0, 0, 0);
        }
    }
#pragma unroll
    for (int t2 = 0; t2 < 8; ++t2) {
        const int col = t2 * 16 + cl;
        const float bv = bias[col];
#pragma unroll
        for (int q = 0; q < 4; ++q) {
            const int rr = rbeg + wave * 16 + g * 4 + q;
            if (rr < nN)
                out[(size_t)rr * IN_F + col] = acc[t2][q] * di[q] + bv;
        }
    }
}

extern "C" void kernel_launch(void* const* d_in, const int* in_sizes, int n_in,
                              void* d_out, int out_size, void* d_ws, size_t ws_size,
                              hipStream_t stream) {
    const float* feat = (const float*)d_in[0];
    const int*   src  = (const int*)d_in[1];
    const int*   dst  = (const int*)d_in[2];
    const float* W    = (const float*)d_in[3];
    const float* bias = (const float*)d_in[4];
    float*       out  = (float*)d_out;

    const int nE = in_sizes[1];
    const int nN = in_sizes[0] / IN_F;
    const int NR = (nN + RANGE - 1) / RANGE;   // 782 coarse ranges

    // workspace (~20.1MB):
    //  [0, 6.4M)      srcpart [HCS][nN]  (K1->K2)  | pairs uint2[nE] (K3->K4, alias)
    //  [6.4M, 19.2M)  h bf16 [nN][128]   (K2->K4)
    //  then ctab [NC][NR], range_base[NRP+2], wt[128*128] bf16
    char* base = (char*)d_ws;
    int*            srcpart    = (int*)base;
    uint2*          pairs      = (uint2*)base;                       // alias (srcpart dead after K2)
    unsigned short* h          = (unsigned short*)(base + (size_t)HCS * nN * 4);
    int*            ctab       = (int*)(h + (size_t)nN * IN_F);
    int*            range_base = ctab + (size_t)NC * NR;
    unsigned short* wt         = (unsigned short*)(range_base + NRP + 2);

    const int SCB = (nN + 7) / 8;              // scale blocks (8 nodes each)
    const int WB  = (128 * 128 + 255) / 256;   // wt convert blocks

    k_hist <<<HRH * HCS + NC, 256, 0, stream>>>(src, dst, srcpart, ctab, nN, nE, NR);
    k_prep2<<<SCB + 1 + WB, 256, 0, stream>>>(feat, srcpart, h, ctab, range_base, W, wt,
                                              nN, nE, NR, SCB);
    k_place<<<NC, 256, 0, stream>>>(src, dst, ctab, range_base, pairs, nE, NR);
    k_main <<<NR, 256, 0, stream>>>(h, pairs, range_base, wt, bias, out, nN);
}

// Round 16
// 121.568 us; speedup vs baseline: 6.9403x; 6.9403x over previous
//
#include <hip/hip_runtime.h>

#define IN_F 128
#define HRH 4            // hist node-ranges (LDS 50KB)
#define HCD 32           // dst chunks (= bin chunkoff table)
#define HCS 32           // src chunks (degree count only)
#define HRB 16           // bin node-ranges (LDS cursor 12.5KB)
#define HIST_RS 12544    // >= ceil(nN/HRH) for nN=50000
#define BIN_RS 3136      // >= ceil(nN/HRB)
#define LROW 68          // LDS tile row stride in uints (272B: conflict-free A-frag reads)

typedef __attribute__((ext_vector_type(8))) short bf16x8;
typedef __attribute__((ext_vector_type(4))) float f32x4;

static __device__ __forceinline__ unsigned short f2bf(float x) {
    unsigned u = __float_as_uint(x);
    unsigned r = (u + 0x7FFFu + ((u >> 16) & 1u)) >> 16;
    return (unsigned short)r;
}

#define RFL(x) __builtin_amdgcn_readfirstlane(x)

// ---------------- privatized histograms: dst (32 chunks) + src (32 chunks) ----
__global__ __launch_bounds__(256) void k_hist(const int* __restrict__ src,
                                              const int* __restrict__ dst,
                                              int* __restrict__ dstpart,
                                              int* __restrict__ srcpart,
                                              int* __restrict__ cursor,
                                              int nN, int nE) {
    __shared__ int h[HIST_RS];
    if (blockIdx.x == 0 && threadIdx.x == 0) *cursor = 0;  // for k_merge
    int bid = blockIdx.x;
    const int* key;
    int* part;
    int r, c, nch;
    if (bid < HRH * HCD) {
        key = dst; part = dstpart; nch = HCD;
        r = bid / HCD; c = bid % HCD;
    } else {
        bid -= HRH * HCD;
        key = src; part = srcpart; nch = HCS;
        r = bid / HCS; c = bid % HCS;
    }
    const int rs   = (nN + HRH - 1) / HRH;
    const int rbeg = r * rs;
    const int rsize = min(rs, nN - rbeg);
    if (rsize <= 0) return;

    for (int i = threadIdx.x; i < rsize; i += 256) h[i] = 0;
    __syncthreads();

    const int chunk = (nE + nch - 1) / nch;
    const int ebeg = c * chunk;
    const int eend = min(ebeg + chunk, nE);

    if ((ebeg & 3) == 0) {
        for (int i = ebeg + threadIdx.x * 4; i < eend; i += 256 * 4) {
            if (i + 3 < eend) {
                const int4 k4 = *reinterpret_cast<const int4*>(key + i);
                int a;
                a = k4.x - rbeg; if ((unsigned)a < (unsigned)rsize) atomicAdd(&h[a], 1);
                a = k4.y - rbeg; if ((unsigned)a < (unsigned)rsize) atomicAdd(&h[a], 1);
                a = k4.z - rbeg; if ((unsigned)a < (unsigned)rsize) atomicAdd(&h[a], 1);
                a = k4.w - rbeg; if ((unsigned)a < (unsigned)rsize) atomicAdd(&h[a], 1);
            } else {
                for (int j = i; j < eend; ++j) {
                    int a = key[j] - rbeg;
                    if ((unsigned)a < (unsigned)rsize) atomicAdd(&h[a], 1);
                }
            }
        }
    } else {
        for (int i = ebeg + threadIdx.x; i < eend; i += 256) {
            int a = key[i] - rbeg;
            if ((unsigned)a < (unsigned)rsize) atomicAdd(&h[a], 1);
        }
    }
    __syncthreads();

    int* pout = part + (size_t)c * nN + rbeg;
    for (int i = threadIdx.x; i < rsize; i += 256) pout[i] = h[i];
}

// ---------------- merge + in-kernel placement (wave-scan + cursor atomic) ----
__global__ __launch_bounds__(256) void k_merge(
    int* __restrict__ dstpart, const int* __restrict__ srcpart,
    int* __restrict__ cnt_pad, int* __restrict__ creal, int* __restrict__ offs,
    float* __restrict__ dinv_out, float* __restrict__ dinv_in,
    int* __restrict__ cursor, int nN) {
    const int n = blockIdx.x * blockDim.x + threadIdx.x;
    const int lane = threadIdx.x & 63;
    int s = 0, run = 0;
    if (n < nN) {
#pragma unroll 4
        for (int c = 0; c < HCS; ++c) s += srcpart[(size_t)c * nN + n];
#pragma unroll 4
        for (int c = 0; c < HCD; ++c) {
            const size_t idx = (size_t)c * nN + n;
            int v = dstpart[idx];
            dstpart[idx] = run;
            run += v;
        }
    }
    const int padded = (n < nN) ? ((run + 7) & ~7) : 0;
    int x = padded;
#pragma unroll
    for (int d = 1; d < 64; d <<= 1) {
        int y = __shfl_up(x, d);
        if (lane >= d) x += y;
    }
    const int total = __shfl(x, 63);
    int base = 0;
    if (lane == 63 && total > 0) base = atomicAdd(cursor, total);
    base = __shfl(base, 63);
    if (n < nN) {
        offs[n]     = base + x - padded;
        cnt_pad[n]  = padded;
        creal[n]    = run;
        dinv_out[n] = rsqrtf(fmaxf((float)s, 1.0f));
        dinv_in[n]  = rsqrtf(fmaxf((float)run, 1.0f));
    }
}

// ---------------- bucket edges by dst via LDS cursors (no global atomics) ----
__global__ __launch_bounds__(256) void k_bin2(const int* __restrict__ src,
                                              const int* __restrict__ dst,
                                              const int* __restrict__ offs,
                                              const int* __restrict__ chunkoff,
                                              int* __restrict__ eidx, int nN, int nE) {
    __shared__ int cur[BIN_RS];
    const int bid = blockIdx.x;
    const int r = bid / HCD;
    const int c = bid % HCD;
    const int rs = (nN + HRB - 1) / HRB;
    const int rbeg = r * rs;
    const int rsize = min(rs, nN - rbeg);
    if (rsize <= 0) return;

    for (int i = threadIdx.x; i < rsize; i += 256)
        cur[i] = offs[rbeg + i] + chunkoff[(size_t)c * nN + rbeg + i];
    __syncthreads();

    const int chunk = (nE + HCD - 1) / HCD;
    const int ebeg = c * chunk;
    const int eend = min(ebeg + chunk, nE);
    for (int i = ebeg + threadIdx.x * 4; i < eend; i += 256 * 4) {
        if (i + 3 < eend) {
            const int4 d4 = *reinterpret_cast<const int4*>(dst + i);
            int d;
            d = d4.x - rbeg; if ((unsigned)d < (unsigned)rsize) { int p = atomicAdd(&cur[d], 1); eidx[p] = src[i + 0]; }
            d = d4.y - rbeg; if ((unsigned)d < (unsigned)rsize) { int p = atomicAdd(&cur[d], 1); eidx[p] = src[i + 1]; }
            d = d4.z - rbeg; if ((unsigned)d < (unsigned)rsize) { int p = atomicAdd(&cur[d], 1); eidx[p] = src[i + 2]; }
            d = d4.w - rbeg; if ((unsigned)d < (unsigned)rsize) { int p = atomicAdd(&cur[d], 1); eidx[p] = src[i + 3]; }
        } else {
            for (int j = i; j < eend; ++j) {
                int d = dst[j] - rbeg;
                if ((unsigned)d < (unsigned)rsize) { int p = atomicAdd(&cur[d], 1); eidx[p] = src[j]; }
            }
        }
    }
}

// ---------------- fused prep: scale | pad | wprep (block-range dispatch) -----
__global__ __launch_bounds__(256) void k_prep(
    const float* __restrict__ feat, const float* __restrict__ dinv,
    unsigned short* __restrict__ h,
    const int* __restrict__ offs, const int* __restrict__ creal,
    const int* __restrict__ cnt_pad, int* __restrict__ eidx,
    const float* __restrict__ W, unsigned short* __restrict__ wt,
    int nN, int SB, int PB) {
    const int b = blockIdx.x;
    if (b < SB) {
        const int i = b * 256 + threadIdx.x;  // one thread = 4 elems
        if (i >= (nN + 1) * (IN_F / 4)) return;
        const int node = i >> 5;
        const int j = (i & 31) * 4;
        ushort4 o = make_ushort4(0, 0, 0, 0);
        if (node < nN) {
            const float s = dinv[node];
            const float4 v = *reinterpret_cast<const float4*>(feat + (size_t)node * IN_F + j);
            o.x = f2bf(v.x * s);
            o.y = f2bf(v.y * s);
            o.z = f2bf(v.z * s);
            o.w = f2bf(v.w * s);
        }
        *reinterpret_cast<ushort4*>(h + (size_t)node * IN_F + j) = o;
    } else if (b < SB + PB) {
        const int n = (b - SB) * 256 + threadIdx.x;
        if (n >= nN) return;
        const int base = offs[n];
        const int st = base + creal[n];
        const int e  = base + cnt_pad[n];
        for (int i = st; i < e; ++i) eidx[i] = nN;
    } else {
        const int t = (b - SB - PB) * 256 + threadIdx.x;
        if (t >= 128 * 128) return;
        const int col = t >> 7;
        const int k = t & 127;
        wt[col * 128 + k] = f2bf(W[k * 128 + col]);
    }
}

// ---------------- fused gather + GEMM: 8 waves/block, 2 nodes per wave --------
#define ISSUE8(vv, a0, a1)                                                        \
    vv##0 = *reinterpret_cast<const unsigned*>(h + (size_t)RFL(a0.x) * IN_F + lo); \
    vv##1 = *reinterpret_cast<const unsigned*>(h + (size_t)RFL(a0.y) * IN_F + lo); \
    vv##2 = *reinterpret_cast<const unsigned*>(h + (size_t)RFL(a0.z) * IN_F + lo); \
    vv##3 = *reinterpret_cast<const unsigned*>(h + (size_t)RFL(a0.w) * IN_F + lo); \
    vv##4 = *reinterpret_cast<const unsigned*>(h + (size_t)RFL(a1.x) * IN_F + lo); \
    vv##5 = *reinterpret_cast<const unsigned*>(h + (size_t)RFL(a1.y) * IN_F + lo); \
    vv##6 = *reinterpret_cast<const unsigned*>(h + (size_t)RFL(a1.z) * IN_F + lo); \
    vv##7 = *reinterpret_cast<const unsigned*>(h + (size_t)RFL(a1.w) * IN_F + lo);

#define ACC8(vv, ax, ay)                                                            \
    ax += __uint_as_float(vv##0 << 16); ay += __uint_as_float(vv##0 & 0xFFFF0000u); \
    ax += __uint_as_float(vv##1 << 16); ay += __uint_as_float(vv##1 & 0xFFFF0000u); \
    ax += __uint_as_float(vv##2 << 16); ay += __uint_as_float(vv##2 & 0xFFFF0000u); \
    ax += __uint_as_float(vv##3 << 16); ay += __uint_as_float(vv##3 & 0xFFFF0000u); \
    ax += __uint_as_float(vv##4 << 16); ay += __uint_as_float(vv##4 & 0xFFFF0000u); \
    ax += __uint_as_float(vv##5 << 16); ay += __uint_as_float(vv##5 & 0xFFFF0000u); \
    ax += __uint_as_float(vv##6 << 16); ay += __uint_as_float(vv##6 & 0xFFFF0000u); \
    ax += __uint_as_float(vv##7 << 16); ay += __uint_as_float(vv##7 & 0xFFFF0000u);

__global__ __launch_bounds__(512) void k_gg(
    const unsigned short* __restrict__ h, const int* __restrict__ eidx,
    const int* __restrict__ offs, const int* __restrict__ cnt_pad,
    const unsigned short* __restrict__ wt,
    const float* __restrict__ bias, const float* __restrict__ dinv_in,
    float* __restrict__ out, int nN) {
    __shared__ unsigned tile[16 * LROW];
    const int lane = threadIdx.x & 63;
    const int wave = threadIdx.x >> 6;      // 0..7
    const int blk16 = blockIdx.x * 16;
    const size_t lo = (size_t)(lane * 2);

    // ---- phase 1: this wave gathers nodes rA = blk16+2*wave, rB = rA+1 ----
    const int rA = blk16 + wave * 2;
    const int rB = rA + 1;
    int begA = 0, endA = 0, begB = 0, endB = 0;
    if (rA < nN) { begA = RFL(offs[rA]); endA = begA + RFL(cnt_pad[rA]); }
    if (rB < nN) { begB = RFL(offs[rB]); endB = begB + RFL(cnt_pad[rB]); }

    float axA = 0.f, ayA = 0.f, axB = 0.f, ayB = 0.f;
    int iA = begA, iB = begB;
    int4 a0, a1, b0, b1;
    bool lA = iA < endA, lB = iB < endB;
    if (lA) { a0 = *reinterpret_cast<const int4*>(eidx + RFL(iA));
              a1 = *reinterpret_cast<const int4*>(eidx + RFL(iA) + 4); }
    if (lB) { b0 = *reinterpret_cast<const int4*>(eidx + RFL(iB));
              b1 = *reinterpret_cast<const int4*>(eidx + RFL(iB) + 4); }

    while (lA | lB) {
        unsigned vA0, vA1, vA2, vA3, vA4, vA5, vA6, vA7;
        unsigned vB0, vB1, vB2, vB3, vB4, vB5, vB6, vB7;
        if (lA) { ISSUE8(vA, a0, a1) }
        if (lB) { ISSUE8(vB, b0, b1) }
        if (iA + 8 < endA) { a0 = *reinterpret_cast<const int4*>(eidx + RFL(iA) + 8);
                             a1 = *reinterpret_cast<const int4*>(eidx + RFL(iA) + 12); }
        if (iB + 8 < endB) { b0 = *reinterpret_cast<const int4*>(eidx + RFL(iB) + 8);
                             b1 = *reinterpret_cast<const int4*>(eidx + RFL(iB) + 12); }
        if (lA) { ACC8(vA, axA, ayA) iA += 8; }
        if (lB) { ACC8(vB, axB, ayB) iB += 8; }
        lA = iA < endA; lB = iB < endB;
    }

    tile[(wave * 2 + 0) * LROW + lane] = ((unsigned)f2bf(ayA) << 16) | (unsigned)f2bf(axA);
    tile[(wave * 2 + 1) * LROW + lane] = ((unsigned)f2bf(ayB) << 16) | (unsigned)f2bf(axB);
    __syncthreads();

    // ---- phase 2: [16 x 128] @ W — each wave computes one 16-col tile ----
    const int g = lane >> 4;       // k-group / C-row group
    const int cl = lane & 15;      // col-in-tile / A-row

    float di[4];
#pragma unroll
    for (int q = 0; q < 4; ++q)
        di[q] = dinv_in[min(blk16 + g * 4 + q, nN - 1)];

    f32x4 acc = (f32x4){0.f, 0.f, 0.f, 0.f};
    const int col = wave * 16 + cl;

#pragma unroll
    for (int s = 0; s < 4; ++s) {
        const bf16x8 a = *reinterpret_cast<const bf16x8*>(tile + cl * LROW + s * 16 + g * 4);
        const bf16x8 b = *reinterpret_cast<const bf16x8*>(wt + (size_t)col * IN_F + s * 32 + g * 8);
        acc = __builtin_amdgcn_mfma_f32_16x16x32_bf16(a, b, acc, 0, 0, 0);
    }

    const float bv = bias[col];
#pragma unroll
    for (int q = 0; q < 4; ++q) {
        const int rr = blk16 + g * 4 + q;
        if (rr < nN)
            out[(size_t)rr * IN_F + col] = acc[q] * di[q] + bv;
    }
}

extern "C" void kernel_launch(void* const* d_in, const int* in_sizes, int n_in,
                              void* d_out, int out_size, void* d_ws, size_t ws_size,
                              hipStream_t stream) {
    const float* feat = (const float*)d_in[0];
    const int*   src  = (const int*)d_in[1];
    const int*   dst  = (const int*)d_in[2];
    const float* W    = (const float*)d_in[3];
    const float* bias = (const float*)d_in[4];
    float*       out  = (float*)d_out;

    const int nE = in_sizes[1];
    const int nN = in_sizes[0] / IN_F;

    // workspace (aliased, ~20MB):
    //  [0, 6.4M)       dstpart [HCD=32][nN] (hist->merge->bin2) \ both overlaid by
    //  [6.4M, 12.8M)   srcpart [HCS=32][nN] (hist->merge)       / h bf16 (nN+1 rows, prep->gg)
    //  [12.8M+256, ..) eidx padded (bin2/prep->gg)  — placed after h's zero row
    //  tail: wt, cnt_pad, creal, dinv_out, dinv_in, offs, cursor
    char* base = (char*)d_ws;
    int*            dstpart  = (int*)base;
    int*            srcpart  = (int*)(base + (size_t)HCD * nN * 4);
    unsigned short* h        = (unsigned short*)base;
    int*            eidx     = (int*)(h + (size_t)(nN + 1) * IN_F);   // after h (incl. zero row)
    int*            eidx_end = eidx + nE + 8 * nN;  // capacity bound
    unsigned short* wt       = (unsigned short*)eidx_end;
    int*            cnt_pad  = (int*)(wt + 128 * 128);
    int*            creal    = cnt_pad + nN + 4;
    float*          dinv_out = (float*)(creal + nN + 4);
    float*          dinv_in  = dinv_out + nN;
    int*            offs     = (int*)(dinv_in + nN);
    int*            cursor   = offs + nN + 4;

    const int SB = ((nN + 1) * (IN_F / 4) + 255) / 256;  // scale blocks
    const int PB = (nN + 255) / 256;                     // pad blocks
    const int WB = (128 * 128 + 255) / 256;              // wprep blocks

    k_hist <<<HRH * (HCD + HCS), 256, 0, stream>>>(src, dst, dstpart, srcpart, cursor, nN, nE);
    k_merge<<<(nN + 255) / 256, 256, 0, stream>>>(dstpart, srcpart, cnt_pad, creal, offs,
                                                  dinv_out, dinv_in, cursor, nN);
    k_bin2 <<<HRB * HCD, 256, 0, stream>>>(src, dst, offs, dstpart, eidx, nN, nE);
    k_prep <<<SB + PB + WB, 256, 0, stream>>>(feat, dinv_out, h, offs, creal, cnt_pad,
                                              eidx, W, wt, nN, SB, PB);
    k_gg   <<<(nN + 15) / 16, 512, 0, stream>>>(h, eidx, offs, cnt_pad, wt, bias, dinv_in, out, nN);
}

// Round 17
// 116.268 us; speedup vs baseline: 7.2567x; 1.0456x over previous
//
#include <hip/hip_runtime.h>

#define IN_F 128
#define HRH 4            // hist node-ranges (LDS 50KB)
#define HCD 64           // dst chunks (= bin chunks, chunkoff table)
#define HCS 32           // src chunks (degree count only)
#define HRB 8            // bin node-ranges (LDS cursor 25KB)
#define HIST_RS 12544    // >= ceil(nN/HRH) for nN=50000
#define BIN_RS 6272      // >= ceil(nN/HRB)
#define LROW 68          // LDS tile row stride in uints (272B: conflict-free A-frag reads)

typedef __attribute__((ext_vector_type(8))) short bf16x8;
typedef __attribute__((ext_vector_type(4))) float f32x4;

static __device__ __forceinline__ unsigned short f2bf(float x) {
    unsigned u = __float_as_uint(x);
    unsigned r = (u + 0x7FFFu + ((u >> 16) & 1u)) >> 16;
    return (unsigned short)r;
}

#define RFL(x) __builtin_amdgcn_readfirstlane(x)

// ---------------- privatized histograms: dst (64 chunks) + src (32 chunks) ----
__global__ __launch_bounds__(256) void k_hist(const int* __restrict__ src,
                                              const int* __restrict__ dst,
                                              int* __restrict__ dstpart,
                                              int* __restrict__ srcpart,
                                              int* __restrict__ cursor,
                                              int nN, int nE) {
    __shared__ int h[HIST_RS];
    if (blockIdx.x == 0 && threadIdx.x == 0) *cursor = 0;  // for k_merge
    int bid = blockIdx.x;
    const int* key;
    int* part;
    int r, c, nch;
    if (bid < HRH * HCD) {
        key = dst; part = dstpart; nch = HCD;
        r = bid / HCD; c = bid % HCD;
    } else {
        bid -= HRH * HCD;
        key = src; part = srcpart; nch = HCS;
        r = bid / HCS; c = bid % HCS;
    }
    const int rs   = (nN + HRH - 1) / HRH;
    const int rbeg = r * rs;
    const int rsize = min(rs, nN - rbeg);
    if (rsize <= 0) return;

    for (int i = threadIdx.x; i < rsize; i += 256) h[i] = 0;
    __syncthreads();

    const int chunk = (nE + nch - 1) / nch;
    const int ebeg = c * chunk;
    const int eend = min(ebeg + chunk, nE);

    if ((ebeg & 3) == 0) {
        for (int i = ebeg + threadIdx.x * 4; i < eend; i += 256 * 4) {
            if (i + 3 < eend) {
                const int4 k4 = *reinterpret_cast<const int4*>(key + i);
                int a;
                a = k4.x - rbeg; if ((unsigned)a < (unsigned)rsize) atomicAdd(&h[a], 1);
                a = k4.y - rbeg; if ((unsigned)a < (unsigned)rsize) atomicAdd(&h[a], 1);
                a = k4.z - rbeg; if ((unsigned)a < (unsigned)rsize) atomicAdd(&h[a], 1);
                a = k4.w - rbeg; if ((unsigned)a < (unsigned)rsize) atomicAdd(&h[a], 1);
            } else {
                for (int j = i; j < eend; ++j) {
                    int a = key[j] - rbeg;
                    if ((unsigned)a < (unsigned)rsize) atomicAdd(&h[a], 1);
                }
            }
        }
    } else {
        for (int i = ebeg + threadIdx.x; i < eend; i += 256) {
            int a = key[i] - rbeg;
            if ((unsigned)a < (unsigned)rsize) atomicAdd(&h[a], 1);
        }
    }
    __syncthreads();

    int* pout = part + (size_t)c * nN + rbeg;
    for (int i = threadIdx.x; i < rsize; i += 256) pout[i] = h[i];
}

// ---------------- merge + in-kernel placement (wave-scan + cursor atomic) ----
__global__ __launch_bounds__(256) void k_merge(
    int* __restrict__ dstpart, const int* __restrict__ srcpart,
    int* __restrict__ cnt_pad, int* __restrict__ creal, int* __restrict__ offs,
    float* __restrict__ dinv_out, float* __restrict__ dinv_in,
    int* __restrict__ cursor, int nN) {
    const int n = blockIdx.x * blockDim.x + threadIdx.x;
    const int lane = threadIdx.x & 63;
    int s = 0, run = 0;
    if (n < nN) {
#pragma unroll 4
        for (int c = 0; c < HCS; ++c) s += srcpart[(size_t)c * nN + n];
#pragma unroll 4
        for (int c = 0; c < HCD; ++c) {
            const size_t idx = (size_t)c * nN + n;
            int v = dstpart[idx];
            dstpart[idx] = run;
            run += v;
        }
    }
    const int padded = (n < nN) ? ((run + 7) & ~7) : 0;
    int x = padded;
#pragma unroll
    for (int d = 1; d < 64; d <<= 1) {
        int y = __shfl_up(x, d);
        if (lane >= d) x += y;
    }
    const int total = __shfl(x, 63);
    int base = 0;
    if (lane == 63 && total > 0) base = atomicAdd(cursor, total);
    base = __shfl(base, 63);
    if (n < nN) {
        offs[n]     = base + x - padded;
        cnt_pad[n]  = padded;
        creal[n]    = run;
        dinv_out[n] = rsqrtf(fmaxf((float)s, 1.0f));
        dinv_in[n]  = rsqrtf(fmaxf((float)run, 1.0f));
    }
}

// ---------------- bucket edges by dst via LDS cursors (no global atomics) ----
__global__ __launch_bounds__(256) void k_bin2(const int* __restrict__ src,
                                              const int* __restrict__ dst,
                                              const int* __restrict__ offs,
                                              const int* __restrict__ chunkoff,
                                              int* __restrict__ eidx, int nN, int nE) {
    __shared__ int cur[BIN_RS];
    const int bid = blockIdx.x;
    const int r = bid / HCD;
    const int c = bid % HCD;
    const int rs = (nN + HRB - 1) / HRB;
    const int rbeg = r * rs;
    const int rsize = min(rs, nN - rbeg);
    if (rsize <= 0) return;

    for (int i = threadIdx.x; i < rsize; i += 256)
        cur[i] = offs[rbeg + i] + chunkoff[(size_t)c * nN + rbeg + i];
    __syncthreads();

    const int chunk = (nE + HCD - 1) / HCD;
    const int ebeg = c * chunk;
    const int eend = min(ebeg + chunk, nE);
    for (int i = ebeg + threadIdx.x * 4; i < eend; i += 256 * 4) {
        if (i + 3 < eend) {
            const int4 d4 = *reinterpret_cast<const int4*>(dst + i);
            int d;
            d = d4.x - rbeg; if ((unsigned)d < (unsigned)rsize) { int p = atomicAdd(&cur[d], 1); eidx[p] = src[i + 0]; }
            d = d4.y - rbeg; if ((unsigned)d < (unsigned)rsize) { int p = atomicAdd(&cur[d], 1); eidx[p] = src[i + 1]; }
            d = d4.z - rbeg; if ((unsigned)d < (unsigned)rsize) { int p = atomicAdd(&cur[d], 1); eidx[p] = src[i + 2]; }
            d = d4.w - rbeg; if ((unsigned)d < (unsigned)rsize) { int p = atomicAdd(&cur[d], 1); eidx[p] = src[i + 3]; }
        } else {
            for (int j = i; j < eend; ++j) {
                int d = dst[j] - rbeg;
                if ((unsigned)d < (unsigned)rsize) { int p = atomicAdd(&cur[d], 1); eidx[p] = src[j]; }
            }
        }
    }
}

// ---------------- fused prep: scale | pad | wprep (block-range dispatch) -----
__global__ __launch_bounds__(256) void k_prep(
    const float* __restrict__ feat, const float* __restrict__ dinv,
    unsigned short* __restrict__ h,
    const int* __restrict__ offs, const int* __restrict__ creal,
    const int* __restrict__ cnt_pad, int* __restrict__ eidx,
    const float* __restrict__ W, unsigned short* __restrict__ wt,
    int nN, int SB, int PB) {
    const int b = blockIdx.x;
    if (b < SB) {
        const int i = b * 256 + threadIdx.x;  // one thread = 4 elems
        if (i >= (nN + 1) * (IN_F / 4)) return;
        const int node = i >> 5;
        const int j = (i & 31) * 4;
        ushort4 o = make_ushort4(0, 0, 0, 0);
        if (node < nN) {
            const float s = dinv[node];
            const float4 v = *reinterpret_cast<const float4*>(feat + (size_t)node * IN_F + j);
            o.x = f2bf(v.x * s);
            o.y = f2bf(v.y * s);
            o.z = f2bf(v.z * s);
            o.w = f2bf(v.w * s);
        }
        *reinterpret_cast<ushort4*>(h + (size_t)node * IN_F + j) = o;
    } else if (b < SB + PB) {
        const int n = (b - SB) * 256 + threadIdx.x;
        if (n >= nN) return;
        const int base = offs[n];
        const int st = base + creal[n];
        const int e  = base + cnt_pad[n];
        for (int i = st; i < e; ++i) eidx[i] = nN;
    } else {
        const int t = (b - SB - PB) * 256 + threadIdx.x;
        if (t >= 128 * 128) return;
        const int col = t >> 7;
        const int k = t & 127;
        wt[col * 128 + k] = f2bf(W[k * 128 + col]);
    }
}

// ---------------- fused gather + GEMM: 8 waves/block, 2 nodes per wave --------
#define ISSUE8(vv, a0, a1)                                                        \
    vv##0 = *reinterpret_cast<const unsigned*>(h + (size_t)RFL(a0.x) * IN_F + lo); \
    vv##1 = *reinterpret_cast<const unsigned*>(h + (size_t)RFL(a0.y) * IN_F + lo); \
    vv##2 = *reinterpret_cast<const unsigned*>(h + (size_t)RFL(a0.z) * IN_F + lo); \
    vv##3 = *reinterpret_cast<const unsigned*>(h + (size_t)RFL(a0.w) * IN_F + lo); \
    vv##4 = *reinterpret_cast<const unsigned*>(h + (size_t)RFL(a1.x) * IN_F + lo); \
    vv##5 = *reinterpret_cast<const unsigned*>(h + (size_t)RFL(a1.y) * IN_F + lo); \
    vv##6 = *reinterpret_cast<const unsigned*>(h + (size_t)RFL(a1.z) * IN_F + lo); \
    vv##7 = *reinterpret_cast<const unsigned*>(h + (size_t)RFL(a1.w) * IN_F + lo);

#define ACC8(vv, ax, ay)                                                            \
    ax += __uint_as_float(vv##0 << 16); ay += __uint_as_float(vv##0 & 0xFFFF0000u); \
    ax += __uint_as_float(vv##1 << 16); ay += __uint_as_float(vv##1 & 0xFFFF0000u); \
    ax += __uint_as_float(vv##2 << 16); ay += __uint_as_float(vv##2 & 0xFFFF0000u); \
    ax += __uint_as_float(vv##3 << 16); ay += __uint_as_float(vv##3 & 0xFFFF0000u); \
    ax += __uint_as_float(vv##4 << 16); ay += __uint_as_float(vv##4 & 0xFFFF0000u); \
    ax += __uint_as_float(vv##5 << 16); ay += __uint_as_float(vv##5 & 0xFFFF0000u); \
    ax += __uint_as_float(vv##6 << 16); ay += __uint_as_float(vv##6 & 0xFFFF0000u); \
    ax += __uint_as_float(vv##7 << 16); ay += __uint_as_float(vv##7 & 0xFFFF0000u);

__global__ __launch_bounds__(512) void k_gg(
    const unsigned short* __restrict__ h, const int* __restrict__ eidx,
    const int* __restrict__ offs, const int* __restrict__ cnt_pad,
    const unsigned short* __restrict__ wt,
    const float* __restrict__ bias, const float* __restrict__ dinv_in,
    float* __restrict__ out, int nN) {
    __shared__ unsigned tile[16 * LROW];
    const int lane = threadIdx.x & 63;
    const int wave = threadIdx.x >> 6;      // 0..7
    const int blk16 = blockIdx.x * 16;
    const size_t lo = (size_t)(lane * 2);

    // ---- phase 1: this wave gathers nodes rA = blk16+2*wave, rB = rA+1 ----
    const int rA = blk16 + wave * 2;
    const int rB = rA + 1;
    int begA = 0, endA = 0, begB = 0, endB = 0;
    if (rA < nN) { begA = RFL(offs[rA]); endA = begA + RFL(cnt_pad[rA]); }
    if (rB < nN) { begB = RFL(offs[rB]); endB = begB + RFL(cnt_pad[rB]); }

    float axA = 0.f, ayA = 0.f, axB = 0.f, ayB = 0.f;
    int iA = begA, iB = begB;
    int4 a0, a1, b0, b1;
    bool lA = iA < endA, lB = iB < endB;
    if (lA) { a0 = *reinterpret_cast<const int4*>(eidx + RFL(iA));
              a1 = *reinterpret_cast<const int4*>(eidx + RFL(iA) + 4); }
    if (lB) { b0 = *reinterpret_cast<const int4*>(eidx + RFL(iB));
              b1 = *reinterpret_cast<const int4*>(eidx + RFL(iB) + 4); }

    while (lA | lB) {
        unsigned vA0, vA1, vA2, vA3, vA4, vA5, vA6, vA7;
        unsigned vB0, vB1, vB2, vB3, vB4, vB5, vB6, vB7;
        if (lA) { ISSUE8(vA, a0, a1) }
        if (lB) { ISSUE8(vB, b0, b1) }
        if (iA + 8 < endA) { a0 = *reinterpret_cast<const int4*>(eidx + RFL(iA) + 8);
                             a1 = *reinterpret_cast<const int4*>(eidx + RFL(iA) + 12); }
        if (iB + 8 < endB) { b0 = *reinterpret_cast<const int4*>(eidx + RFL(iB) + 8);
                             b1 = *reinterpret_cast<const int4*>(eidx + RFL(iB) + 12); }
        if (lA) { ACC8(vA, axA, ayA) iA += 8; }
        if (lB) { ACC8(vB, axB, ayB) iB += 8; }
        lA = iA < endA; lB = iB < endB;
    }

    tile[(wave * 2 + 0) * LROW + lane] = ((unsigned)f2bf(ayA) << 16) | (unsigned)f2bf(axA);
    tile[(wave * 2 + 1) * LROW + lane] = ((unsigned)f2bf(ayB) << 16) | (unsigned)f2bf(axB);
    __syncthreads();

    // ---- phase 2: [16 x 128] @ W — each wave computes one 16-col tile ----
    const int g = lane >> 4;       // k-group / C-row group
    const int cl = lane & 15;      // col-in-tile / A-row

    float di[4];
#pragma unroll
    for (int q = 0; q < 4; ++q)
        di[q] = dinv_in[min(blk16 + g * 4 + q, nN - 1)];

    f32x4 acc = (f32x4){0.f, 0.f, 0.f, 0.f};
    const int col = wave * 16 + cl;

#pragma unroll
    for (int s = 0; s < 4; ++s) {
        const bf16x8 a = *reinterpret_cast<const bf16x8*>(tile + cl * LROW + s * 16 + g * 4);
        const bf16x8 b = *reinterpret_cast<const bf16x8*>(wt + (size_t)col * IN_F + s * 32 + g * 8);
        acc = __builtin_amdgcn_mfma_f32_16x16x32_bf16(a, b, acc, 0, 0, 0);
    }

    const float bv = bias[col];
#pragma unroll
    for (int q = 0; q < 4; ++q) {
        const int rr = blk16 + g * 4 + q;
        if (rr < nN)
            out[(size_t)rr * IN_F + col] = acc[q] * di[q] + bv;
    }
}

extern "C" void kernel_launch(void* const* d_in, const int* in_sizes, int n_in,
                              void* d_out, int out_size, void* d_ws, size_t ws_size,
                              hipStream_t stream) {
    const float* feat = (const float*)d_in[0];
    const int*   src  = (const int*)d_in[1];
    const int*   dst  = (const int*)d_in[2];
    const float* W    = (const float*)d_in[3];
    const float* bias = (const float*)d_in[4];
    float*       out  = (float*)d_out;

    const int nE = in_sizes[1];
    const int nN = in_sizes[0] / IN_F;

    char* base = (char*)d_ws;
    int*            dstpart  = (int*)base;
    int*            srcpart  = (int*)(base + (size_t)HCD * nN * 4);
    unsigned short* h        = (unsigned short*)base;
    int*            eidx     = (int*)(base + (size_t)(HCD + HCS) * nN * 4);
    int*            eidx_end = eidx + nE + 8 * nN;  // capacity bound
    unsigned short* wt       = (unsigned short*)eidx_end;
    int*            cnt_pad  = (int*)(wt + 128 * 128);
    int*            creal    = cnt_pad + nN + 4;
    float*          dinv_out = (float*)(creal + nN + 4);
    float*          dinv_in  = dinv_out + nN;
    int*            offs     = (int*)(dinv_in + nN);
    int*            cursor   = offs + nN + 4;

    const int SB = ((nN + 1) * (IN_F / 4) + 255) / 256;  // scale blocks
    const int PB = (nN + 255) / 256;                     // pad blocks
    const int WB = (128 * 128 + 255) / 256;              // wprep blocks

    k_hist <<<HRH * (HCD + HCS), 256, 0, stream>>>(src, dst, dstpart, srcpart, cursor, nN, nE);
    k_merge<<<(nN + 255) / 256, 256, 0, stream>>>(dstpart, srcpart, cnt_pad, creal, offs,
                                                  dinv_out, dinv_in, cursor, nN);
    k_bin2 <<<HRB * HCD, 256, 0, stream>>>(src, dst, offs, dstpart, eidx, nN, nE);
    k_prep <<<SB + PB + WB, 256, 0, stream>>>(feat, dinv_out, h, offs, creal, cnt_pad,
                                              eidx, W, wt, nN, SB, PB);
    k_gg   <<<(nN + 15) / 16, 512, 0, stream>>>(h, eidx, offs, cnt_pad, wt, bias, dinv_in, out, nN);
}